// Round 6
// baseline (242.080 us; speedup 1.0000x reference)
//
#include <hip/hip_runtime.h>
#include <hip/hip_fp16.h>
#include <math.h>

// Kobayashi dendrite single timestep, B=4, H=W=2048, fp32, periodic BCs.
// Round 6: fp32 sphi tile (no cvt tax, better precision), fp16 spk/se2 only;
// wave-uniform (readfirstlane) row addressing -> SALU; fully unrolled
// phase-3 sweep -> immediate-offset ds reads; tempr pipelined one row ahead.

#define Bz 4
#define Hd 2048
#define Wd 2048
#define TX 64
#define TY 32
#define PW 68          // phi tile width  (halo 2)
#define PH 36          // phi tile height (halo 2)
#define QW 66          // prod tile width  (halo 1)
#define QH 34          // prod tile height (halo 1)

#define INVD2   1111.11111111111f      // 1/0.03^2
#define K1      277.777777777778f      // (1/(2*0.03))^2  (raw-diff fold)
#define DT_TAU  0.333333333333333f     // 1e-4 / 3e-4
#define DTc     1e-4f
#define KAPPAc  1.8f
#define EPSB    0.01f
#define DELTAc  0.02f
#define ANISOc  6.0f
#define A_PI    0.2864788975654116f    // 0.9/pi
#define GAMMAc  10.0f
#define TEQc    1.0f
#define C6T0    0.3623577544766736f    // cos(1.2)
#define S6T0    0.9320390859672263f    // sin(1.2)
#define PI_2    1.5707963267948966f
#define SC      65536.0f               // fp16 scale for prod/eps^2
#define ISC     (1.0f/65536.0f)

// prod from RAW diffs (1/(2d) cancels in theta; folded into K1 at use).
__device__ __forceinline__ void prodc(float dx, float dy,
                                      float& p1s, float& p2s, float& e2s)
{
    float dx2 = dx * dx;
    float r2  = fmaf(dy, dy, dx2);
    float cn  = fmaf(-dy, dy, dx2);
    float irr = __builtin_amdgcn_rcpf(fmaxf(r2, 1e-20f));
    float c2  = cn * irr;
    float s2  = 2.0f * dx * dy * irr;
    float c22 = c2 * c2;
    float s22 = s2 * s2;
    float c6  = c2 * fmaf(4.0f, c22, -3.0f);
    float s6  = s2 * fmaf(-4.0f, s22, 3.0f);
    float cosA = fmaf(c6, C6T0, s6 * S6T0);
    float sinA = fmaf(s6, C6T0, -c6 * S6T0);
    float eps  = fmaf(EPSB * DELTAc, cosA, EPSB);
    float eesc = eps * (-EPSB * ANISOc * DELTAc * SC) * sinA;
    p1s = eesc * dx;
    p2s = -eesc * dy;
    e2s = eps * eps * SC;
}

// atan(g), g in (0,10]; deg-7 odd minimax on [0,1] + rcp fold. |err|<=6.3e-4.
__device__ __forceinline__ float atan_fast(float g) {
    float r  = __builtin_amdgcn_rcpf(g);
    float a  = fminf(g, r);
    float a2 = a * a;
    float p  = a * fmaf(a2, fmaf(a2, 0.079331f, -0.288679f), 0.995354f);
    return (g <= 1.0f) ? p : PI_2 - p;
}

__global__ __launch_bounds__(256, 6) void dendrite_step(
    const float* __restrict__ phi, const float* __restrict__ tempr,
    float* __restrict__ out_phi, float* __restrict__ out_tempr)
{
    __shared__ float   sphi[PH * PW];        // fp32, 9792 B
    __shared__ __half2 spk[QH * QW];         // .x=p1*SC .y=p2*SC, 8976 B
    __shared__ __half  se2h[QH * QW];        // eps^2*SC, 4488 B

    const int tid = threadIdx.x;
    const int x0 = blockIdx.x * TX;
    const int y0 = blockIdx.y * TY;
    const int base = blockIdx.z * (Hd * Wd);

    // ---- Phase 1: stage phi tile (halo 2) fp32, float2 loads/b64 writes ----
    for (int i = tid; i < PH * PW / 2; i += 256) {
        int r = i / (PW / 2);
        int c2 = i - r * (PW / 2);
        int gy = (y0 + r - 2) & (Hd - 1);
        int gx = (x0 + 2 * c2 - 2) & (Wd - 1);
        *(float2*)&sphi[r * PW + 2 * c2] =
            *(const float2*)(phi + base + gy * Wd + gx);
    }
    __syncthreads();

    // ---- Phase 2: p1/p2/eps^2 (scaled, raw diffs), 2 cells/thread ----
    for (int i = tid; i < QH * (QW / 2); i += 256) {
        int r = i / (QW / 2);
        int c2 = i - r * (QW / 2);
        int cQ = 2 * c2;
        int rowc = (r + 1) * PW + cQ;        // phi row r+1, col cQ
        float2 A  = *(const float2*)&sphi[rowc];        // f0,f1
        float2 Bv = *(const float2*)&sphi[rowc + 2];    // f2,f3
        float u0 = sphi[rowc - PW + 1];
        float u1 = sphi[rowc - PW + 2];
        float d0 = sphi[rowc + PW + 1];
        float d1 = sphi[rowc + PW + 2];

        float p1a, p2a, e2a, p1b, p2b, e2b;
        prodc(Bv.x - A.x, d0 - u0, p1a, p2a, e2a);
        prodc(Bv.y - A.y, d1 - u1, p1b, p2b, e2b);

        int q = r * QW + cQ;
        spk[q]     = __floats2half2_rn(p1a, p2a);
        spk[q + 1] = __floats2half2_rn(p1b, p2b);
        se2h[q]     = __float2half_rn(e2a);
        se2h[q + 1] = __float2half_rn(e2b);
    }
    __syncthreads();

    // ---- Phase 3: fully-unrolled rolling sweep, scalar row addressing ----
    const int tx = tid & 63;
    const int ys = __builtin_amdgcn_readfirstlane((tid >> 6) * 8); // wave-uniform
    const int col = tx + 2;
    const int gx = x0 + tx;
    const int gxm = (gx - 1) & (Wd - 1);
    const int gxp = (gx + 1) & (Wd - 1);

    // phi center column regs (phi rows ys+1, ys+2)
    float pm  = sphi[(ys + 1) * PW + col];
    float pc_ = sphi[(ys + 2) * PW + col];
    // p1 regs (Q rows ys, ys+1)
    float s1m = __low2float(spk[ys * QW + tx + 1]);
    float s1c = __low2float(spk[(ys + 1) * QW + tx + 1]);

    // tempr pipeline: tm = center(y-1); tc* = row y; tn* = row y+1
    float tm = tempr[base + ((y0 + ys - 1) & (Hd - 1)) * Wd + gx];
    {
        int rb0 = base + (y0 + ys) * Wd;
        int rb1 = base + ((y0 + ys + 1) & (Hd - 1)) * Wd;
        float tcl = tempr[rb0 + gxm];
        float tcc = tempr[rb0 + gx];
        float tcr = tempr[rb0 + gxp];
        float tnl = tempr[rb1 + gxm];
        float tnc = tempr[rb1 + gx];
        float tnr = tempr[rb1 + gxp];

        #pragma unroll
        for (int k = 0; k < 8; ++k) {
            int y = ys + k;
            int qrow = y + 1;
            int prow = y + 2;

            float t2l = 0.0f, t2c = 0.0f, t2r = 0.0f;
            if (k < 7) {
                int rb2 = base + ((y0 + y + 2) & (Hd - 1)) * Wd;
                t2l = tempr[rb2 + gxm];
                t2c = tempr[rb2 + gx];
                t2r = tempr[rb2 + gxp];
            }

            float pp  = sphi[(prow + 1) * PW + col];
            float pl  = sphi[prow * PW + col - 1];
            float prr = sphi[prow * PW + col + 1];
            float lap_phi = (pl + prr + pm + pp - 4.0f * pc_) * INVD2;

            float s1p  = __low2float(spk[(qrow + 1) * QW + tx + 1]);
            float sp2l = __high2float(spk[qrow * QW + tx]);
            float sp2r = __high2float(spk[qrow * QW + tx + 2]);
            float term12 = (s1p - s1m + sp2r - sp2l) * (K1 * ISC);
            float e2 = __half2float(se2h[qrow * QW + tx + 1]) * ISC;

            float lap_t = (tcl + tcr + tm + tnc - 4.0f * tcc) * INVD2;

            float mm = A_PI * atan_fast(GAMMAc * (TEQc - tcc));
            float dphi = DT_TAU * (term12 + e2 * lap_phi
                                   + pc_ * (1.0f - pc_) * (pc_ - 0.5f + mm));

            int gidx = base + (y0 + y) * Wd + gx;
            out_phi[gidx] = pc_ + dphi;
            out_tempr[gidx] = fmaf(KAPPAc, dphi, fmaf(DTc, lap_t, tcc));

            // roll
            pm = pc_; pc_ = pp;
            s1m = s1c; s1c = s1p;
            tm = tcc;
            tcl = tnl; tcc = tnc; tcr = tnr;
            tnl = t2l; tnc = t2c; tnr = t2r;
        }
    }
}

extern "C" void kernel_launch(void* const* d_in, const int* in_sizes, int n_in,
                              void* d_out, int out_size, void* d_ws, size_t ws_size,
                              hipStream_t stream) {
    const float* phi = (const float*)d_in[0];
    const float* tempr = (const float*)d_in[1];
    float* out_phi = (float*)d_out;
    float* out_tempr = out_phi + (size_t)Bz * Hd * Wd;

    dim3 grid(Wd / TX, Hd / TY, Bz);
    dendrite_step<<<grid, 256, 0, stream>>>(phi, tempr, out_phi, out_tempr);
}